// Round 25
// baseline (242.720 us; speedup 1.0000x reference)
//
#include <hip/hip_runtime.h>
#include <math.h>

#define BATCH 8
#define CHAN 256
#define HH 128
#define WW 128
#define NMASK 100
#define HWSZ (HH*WW)
#define KD 128

// d_out layout: [logits 800][kernel 102400][scores 800][iam 13107200]
#define OFF_LOGITS 0
#define OFF_KERNEL 800
#define OFF_SCORES (800 + 800*KD)
#define OFF_IAM    (OFF_SCORES + 800)

typedef __attribute__((ext_vector_type(8))) short bf16x8;
typedef __attribute__((ext_vector_type(8))) unsigned short ushort8;
typedef __attribute__((ext_vector_type(4))) float f32x4;

#define WCHUNK (9*7*64*8)   // ushorts per cc-chunk of packed weights (64.5 KB)

__device__ __forceinline__ unsigned short f2bf(float f){
  unsigned int u = __float_as_uint(f);
  u += 0x7fffu + ((u >> 16) & 1u);
  return (unsigned short)(u >> 16);
}

// ---------------- weight pre-pack (+ rowsum zeroing) ----------------
// wr[(((cc*9+tap)*7+nt)*64+l)*8+j] = bf16(W[n][c][kh][kw])
__global__ __launch_bounds__(256) void wpack_kernel(
    const float* __restrict__ cw, unsigned short* __restrict__ wr,
    float* __restrict__ rowsum)
{
  if (blockIdx.x == 0){
    for (int i = threadIdx.x; i < BATCH*NMASK; i += 256) rowsum[i] = 0.f;
  }
  int i = blockIdx.x*256 + threadIdx.x;
  if (i >= 8*9*7*64*8) return;
  int j = i & 7;
  int l = (i >> 3) & 63;
  int rest = i >> 9;
  int nt = rest % 7;
  int tc = rest / 7;
  int tap = tc % 9;
  int cc  = tc / 9;
  int n = nt*16 + (l & 15);
  int c = cc*32 + (l >> 4)*8 + j;
  float v = 0.f;
  if (n < NMASK) v = cw[((size_t)n*CHAN + c)*9 + tap];
  wr[i] = f2bf(v);
}

// ------- feature prepass: fp32 [b][c][p] -> bf16 [b][cg][p][c8] --------------
__global__ __launch_bounds__(256) void prepack_feat_kernel(
    const float* __restrict__ feat, unsigned short* __restrict__ feath)
{
  const int b  = blockIdx.z;
  const int cg = blockIdx.y;
  const int t  = threadIdx.x;
  __shared__ unsigned short lt[8*264];
  const int cl = t >> 5;           // 0..7
  const int po = (t & 31)*8;       // 0..248
  for (int st=0; st<8; ++st){
    const int P0 = blockIdx.x*2048 + st*256;
    const float* src = feat + ((size_t)(b*CHAN + cg*8 + cl))*HWSZ + P0 + po;
    float4 a0 = *(const float4*)src;
    float4 a1 = *(const float4*)(src+4);
    ushort8 u;
    u[0]=f2bf(a0.x); u[1]=f2bf(a0.y); u[2]=f2bf(a0.z); u[3]=f2bf(a0.w);
    u[4]=f2bf(a1.x); u[5]=f2bf(a1.y); u[6]=f2bf(a1.z); u[7]=f2bf(a1.w);
    *(ushort8*)&lt[cl*264 + po] = u;
    __syncthreads();
    ushort8 v;
    #pragma unroll
    for (int c=0;c<8;c++) v[c] = lt[c*264 + t];
    *(ushort8*)&feath[(((size_t)b*32 + cg)*HWSZ + P0 + t)*8] = v;
    __syncthreads();
  }
}

// ------ conv v4e: A-slab LDS, B direct; epilogue also stores bf16 exp(iam) ------
__global__ __launch_bounds__(256,2) void conv_mfma4e_kernel(
    const unsigned short* __restrict__ feath, const unsigned short* __restrict__ wr,
    const float* __restrict__ cb, float* __restrict__ out_iam,
    unsigned short* __restrict__ expi)
{
  const int h0 = blockIdx.x*2;
  const int b  = blockIdx.y;
  const int t  = threadIdx.x;
  const int w  = t >> 6;
  const int l  = t & 63;
  const int lx = l & 15;
  const int lg = l >> 4;

  __shared__ unsigned short lA[WCHUNK];   // 64,512 B, one weight chunk

  f32x4 acc[7][2][2];   // [nt][row][pi]
  #pragma unroll
  for (int nt=0;nt<7;nt++)
    #pragma unroll
    for (int r=0;r<2;r++)
      #pragma unroll
      for (int pi=0;pi<2;pi++) acc[nt][r][pi] = (f32x4){0.f,0.f,0.f,0.f};

  const unsigned short* fb = feath + ((size_t)b*32 + lg)*HWSZ*8;
  const int xb0 = (w*2+0)*16 + lx - 1;
  const int xb1 = (w*2+1)*16 + lx - 1;

  #pragma unroll 1
  for (int cc=0; cc<8; ++cc){
    __syncthreads();   // prior chunk's LDS reads complete
    {
      const unsigned short* src = wr + (size_t)cc*WCHUNK;
      #pragma unroll
      for (int it=0; it<16; ++it){
        int g2 = it*4 + w;
        if (g2 < 63){
          ushort8 v = *(const ushort8*)(src + ((size_t)g2*64 + l)*8);
          *(ushort8*)&lA[((size_t)g2*64 + l)*8] = v;
        }
      }
    }
    __syncthreads();   // slab visible to all waves

    const unsigned short* fcc = fb + (size_t)cc*4*HWSZ*8;
    #pragma unroll
    for (int tap=0; tap<9; ++tap){
      const int kh = tap/3, kw = tap - 3*(tap/3);
      bf16x8 a[7];
      #pragma unroll
      for (int nt=0;nt<7;nt++)
        a[nt] = *(const bf16x8*)&lA[(((size_t)tap*7+nt)*64 + l)*8];
      bf16x8 bv[2][2];
      #pragma unroll
      for (int r=0;r<2;r++){
        const int hr = h0 + r + kh - 1;
        const bool rvv = (unsigned)hr < 128u;
        const int hc = rvv ? hr : 0;
        #pragma unroll
        for (int pi=0;pi<2;pi++){
          const int X = (pi ? xb1 : xb0) + kw;
          const bool xv = (unsigned)X < 128u;
          const int Xc = xv ? X : 0;
          bf16x8 v2 = *(const bf16x8*)&fcc[((size_t)hc*WW + Xc)*8];
          bv[r][pi] = (rvv && xv) ? v2 : (bf16x8)(short)0;
        }
      }
      #pragma unroll
      for (int nt=0;nt<7;nt++)
        #pragma unroll
        for (int r=0;r<2;r++)
          #pragma unroll
          for (int pi=0;pi<2;pi++)
            acc[nt][r][pi] = __builtin_amdgcn_mfma_f32_16x16x32_bf16(
                a[nt], bv[r][pi], acc[nt][r][pi], 0, 0, 0);
    }
  }

  // Epilogue: D col(x)=lane&15, row(mask)=(lane>>4)*4+q.
  #pragma unroll
  for (int nt=0; nt<7; nt++){
    const int n0 = nt*16 + lg*4;
    #pragma unroll
    for (int r=0; r<2; r++){
      #pragma unroll
      for (int pi=0; pi<2; pi++){
        const int xo = (w*2+pi)*16 + lx;
        #pragma unroll
        for (int q=0; q<4; q++){
          int n = n0 + q;
          if (n < NMASK){
            const float v = acc[nt][r][pi][q] + cb[n];
            const size_t idx = ((size_t)b*NMASK + n)*HWSZ + (h0+r)*WW + xo;
            out_iam[idx] = v;
            expi[idx] = f2bf(__expf(v));
          }
        }
      }
    }
  }
}

// ---------------- conv v1 (fallback for small ws: fp32 staging via LDS) ----------
#define LDSX 40
__global__ __launch_bounds__(256) void conv_mfma_kernel(
    const float* __restrict__ feat, const unsigned short* __restrict__ wr,
    const float* __restrict__ cb, float* __restrict__ out_iam,
    unsigned short* __restrict__ expi)
{
  const int h = blockIdx.x;
  const int b = blockIdx.y;
  const int t = threadIdx.x;
  const int w = t >> 6;
  const int l = t & 63;
  const int lx = l & 15;
  const int lg = l >> 4;

  __shared__ unsigned short lds[3*132*LDSX];

  f32x4 acc[7][2];
  #pragma unroll
  for (int nt=0;nt<7;nt++)
    #pragma unroll
    for (int pi=0;pi<2;pi++) acc[nt][pi] = (f32x4){0.f,0.f,0.f,0.f};

  const float* fb = feat + (size_t)b*CHAN*HWSZ;

  for (int cc=0; cc<8; ++cc){
    const int c0 = cc*32;
    __syncthreads();
    for (int gi = t; gi < 1560; gi += 256){
      int xh = gi % 130;
      int q  = gi / 130;
      int cg = q & 3;
      int kh = q >> 2;
      int row = h + kh - 1;
      int xx  = xh - 1;
      bool ok = ((unsigned)row < 128u) & ((unsigned)xx < 128u);
      const float* src = fb + (size_t)(c0 + cg*8)*HWSZ + row*WW + xx;
      ushort8 u;
      #pragma unroll
      for (int j=0;j<8;j++){
        float v = ok ? src[(size_t)j*HWSZ] : 0.f;
        u[j] = f2bf(v);
      }
      *(ushort8*)&lds[(kh*132 + xh)*LDSX + cg*8] = u;
    }
    __syncthreads();

    const unsigned short* wbase = wr + ((size_t)cc*9*7*64 + l)*8;
    #pragma unroll 1
    for (int tap=0; tap<9; ++tap){
      const int kh = tap / 3;
      const int kw = tap - kh*3;
      bf16x8 a[7];
      #pragma unroll
      for (int nt=0; nt<7; nt++)
        a[nt] = *(const bf16x8*)(wbase + ((size_t)(tap*7 + nt))*64*8);
      bf16x8 bfv[2];
      #pragma unroll
      for (int pi=0; pi<2; pi++){
        int xh = (w*2+pi)*16 + lx + kw;
        bfv[pi] = *(const bf16x8*)&lds[(kh*132 + xh)*LDSX + lg*8];
      }
      #pragma unroll
      for (int nt=0; nt<7; nt++)
        #pragma unroll
        for (int pi=0; pi<2; pi++)
          acc[nt][pi] = __builtin_amdgcn_mfma_f32_16x16x32_bf16(
              a[nt], bfv[pi], acc[nt][pi], 0, 0, 0);
    }
  }

  #pragma unroll
  for (int nt=0; nt<7; nt++){
    const int n0 = nt*16 + lg*4;
    #pragma unroll
    for (int pi=0; pi<2; pi++){
      const int xo = (w*2+pi)*16 + lx;
      #pragma unroll
      for (int r=0; r<4; r++){
        int n = n0 + r;
        if (n < NMASK){
          const float v = acc[nt][pi][r] + cb[n];
          const size_t idx = ((size_t)b*NMASK + n)*HWSZ + h*WW + xo;
          out_iam[idx] = v;
          expi[idx] = f2bf(__expf(v));
        }
      }
    }
  }
}

// -------- einsum: A = bf16 exp(iam) direct; rowsum from bf16; bf16 partial ----
// partial_bf[s][b][n][c] = bf16(sum_p expi[n,p]*F[c,p]) (unnormalized).
__global__ __launch_bounds__(256) void einsum_expi_kernel(
  const float* __restrict__ feat, const unsigned short* __restrict__ expi,
  float* __restrict__ rowsum, unsigned short* __restrict__ partial)
{
  const int s = blockIdx.x;
  const int nsplit = gridDim.x;
  const int KC = HWSZ / nsplit;
  const int b = blockIdx.z;
  const int t = threadIdx.x;
  const int w = t >> 6;
  const int l = t & 63;
  const int lx = l & 15;
  const int lg = l >> 4;

  f32x4 acc[7][4];
  #pragma unroll
  for (int nt=0;nt<7;nt++)
    #pragma unroll
    for (int j=0;j<4;j++) acc[nt][j] = (f32x4){0.f,0.f,0.f,0.f};

  float se[7];
  #pragma unroll
  for (int nt=0;nt<7;nt++) se[nt] = 0.f;

  int rown[7];
  #pragma unroll
  for (int nt=0;nt<7;nt++){
    int row = nt*16 + lx;
    if (row >= NMASK) row = NMASK-1;
    rown[nt] = row;
  }

  const float* fb = feat + (size_t)b*CHAN*HWSZ;
  const unsigned short* eb = expi + (size_t)b*NMASK*HWSZ;

  #pragma unroll 2
  for (int ks=0; ks<KC/32; ++ks){
    const int p0 = s*KC + ks*32 + lg*8;
    bf16x8 afr[7];
    #pragma unroll
    for (int nt=0;nt<7;nt++){
      ushort8 u = *(const ushort8*)(eb + (size_t)rown[nt]*HWSZ + p0);
      #pragma unroll
      for (int j=0;j<8;j++)
        se[nt] += __uint_as_float((unsigned)u[j] << 16);
      afr[nt] = *(bf16x8*)&u;
    }
    bf16x8 bfr[4];
    #pragma unroll
    for (int j=0;j<4;j++){
      const float* fp = fb + (size_t)(w*64 + j*16 + lx)*HWSZ + p0;
      float4 b0 = *(const float4*)fp;
      float4 b1 = *(const float4*)(fp+4);
      ushort8 u;
      u[0]=f2bf(b0.x); u[1]=f2bf(b0.y); u[2]=f2bf(b0.z); u[3]=f2bf(b0.w);
      u[4]=f2bf(b1.x); u[5]=f2bf(b1.y); u[6]=f2bf(b1.z); u[7]=f2bf(b1.w);
      bfr[j] = *(bf16x8*)&u;
    }
    #pragma unroll
    for (int nt=0;nt<7;nt++)
      #pragma unroll
      for (int j=0;j<4;j++)
        acc[nt][j] = __builtin_amdgcn_mfma_f32_16x16x32_bf16(
            afr[nt], bfr[j], acc[nt][j], 0, 0, 0);
  }

  // rowsum contribution: reduce across lg groups (same lx), wave 0 only.
  if (w == 0){
    #pragma unroll
    for (int nt=0;nt<7;nt++){
      float sv = se[nt];
      sv += __shfl_xor(sv, 16);
      sv += __shfl_xor(sv, 32);
      int row = nt*16 + l;          // l < 16 lanes are canonical
      if (l < 16 && row < NMASK)
        atomicAdd(&rowsum[b*NMASK + row], sv);
    }
  }

  #pragma unroll
  for (int nt=0;nt<7;nt++){
    #pragma unroll
    for (int j=0;j<4;j++){
      const int c = w*64 + j*16 + lx;
      #pragma unroll
      for (int r=0;r<4;r++){
        int n = nt*16 + lg*4 + r;
        if (n < NMASK)
          partial[(((size_t)b*nsplit + s)*NMASK + n)*CHAN + c] = f2bf(acc[nt][j][r]);
      }
    }
  }
}

// ---------- reduce bf16 partials (scaled by 1/rowsum) + fc + heads ----------
__global__ __launch_bounds__(256) void fc_head_kernel(
  const unsigned short* __restrict__ partial, int nsplit,
  const float* __restrict__ rowsum,
  const float* __restrict__ fc_w, const float* __restrict__ fc_b,
  const float* __restrict__ cls_w, const float* __restrict__ cls_b,
  const float* __restrict__ mk_w, const float* __restrict__ mk_b,
  const float* __restrict__ obj_w, const float* __restrict__ obj_b,
  float* __restrict__ dout)
{
  const int n = blockIdx.x;
  const int b = blockIdx.y;
  const int t = threadIdx.x;
  __shared__ float xs[256];
  __shared__ float xr[256];
  __shared__ float red[256];
  float x = 0.f;
  for (int s=0;s<nsplit;s++)
    x += __uint_as_float((unsigned)partial[(((size_t)b*nsplit+s)*NMASK + n)*CHAN + t] << 16);
  x *= (1.0f / rowsum[b*NMASK + n]);   // softmax normalization, deferred
  xs[t] = x;
  __syncthreads();
  float y = fc_b[t];
  const float* wr2 = fc_w + (size_t)t*CHAN;
  for (int k=0;k<CHAN;k+=4){
    float4 w4 = *(const float4*)&wr2[k];
    y = fmaf(xs[k],w4.x,y); y=fmaf(xs[k+1],w4.y,y);
    y = fmaf(xs[k+2],w4.z,y); y=fmaf(xs[k+3],w4.w,y);
  }
  y = fmaxf(y, 0.f);
  xr[t] = y;
  __syncthreads();
  if (t < KD){
    float ka = mk_b[t];
    const float* mr = mk_w + (size_t)t*CHAN;
    for (int k=0;k<CHAN;k+=4){
      float4 w4 = *(const float4*)&mr[k];
      ka = fmaf(xr[k],w4.x,ka); ka=fmaf(xr[k+1],w4.y,ka);
      ka = fmaf(xr[k+2],w4.z,ka); ka=fmaf(xr[k+3],w4.w,ka);
    }
    dout[OFF_KERNEL + ((size_t)b*NMASK + n)*KD + t] = ka;
  }
  red[t] = xr[t] * cls_w[t];
  __syncthreads();
  for (int s2=128;s2>0;s2>>=1){ if(t<s2) red[t]+=red[t+s2]; __syncthreads(); }
  if (t==0) dout[OFF_LOGITS + (size_t)b*NMASK + n] = red[0] + cls_b[0];
  __syncthreads();
  red[t] = xr[t] * obj_w[t];
  __syncthreads();
  for (int s2=128;s2>0;s2>>=1){ if(t<s2) red[t]+=red[t+s2]; __syncthreads(); }
  if (t==0) dout[OFF_SCORES + (size_t)b*NMASK + n] = red[0] + obj_b[0];
}

extern "C" void kernel_launch(void* const* d_in, const int* in_sizes, int n_in,
                              void* d_out, int out_size, void* d_ws, size_t ws_size,
                              hipStream_t stream)
{
  const float* feat   = (const float*)d_in[0];
  const float* conv_w = (const float*)d_in[1];
  const float* conv_b = (const float*)d_in[2];
  // d_in[3] = softmax_bias: scalar shift, softmax-invariant -> unused
  const float* fc_w   = (const float*)d_in[4];
  const float* fc_b   = (const float*)d_in[5];
  const float* cls_w  = (const float*)d_in[6];
  const float* cls_b  = (const float*)d_in[7];
  const float* mk_w   = (const float*)d_in[8];
  const float* mk_b   = (const float*)d_in[9];
  const float* obj_w  = (const float*)d_in[10];
  const float* obj_b  = (const float*)d_in[11];
  float* dout = (float*)d_out;
  float* iam  = dout + OFF_IAM;

  const size_t statb  = 1600*sizeof(float);                 // rowsum uses 3200
  const size_t wrb    = (size_t)8*WCHUNK*2;                 // 516096
  const size_t feathb = (size_t)BATCH*32*HWSZ*8*2;          // 67,108,864
  const size_t expib  = (size_t)BATCH*NMASK*HWSZ*2;         // 26,214,400

  float* rowsum = (float*)d_ws;
  unsigned short* wr = (unsigned short*)((char*)d_ws + statb);
  char* shared_region = (char*)d_ws + statb + wrb;          // feath | partial alias
  unsigned short* expi = (unsigned short*)(shared_region + feathb);

  wpack_kernel<<<dim3((8*WCHUNK + 255)/256), 256, 0, stream>>>(conv_w, wr, rowsum);

  if (ws_size >= statb + wrb + feathb + expib + 1024){
    // mode A: prepass + v4e conv + expi einsum at ksplit=128 (1024 blocks =
    // 4 blocks/CU, latency-hiding doubled). bf16 partial (52.4 MB) aliases
    // feath (67 MB, disjoint lifetimes); expi separate.
    unsigned short* feath = (unsigned short*)shared_region;
    unsigned short* partial = (unsigned short*)shared_region;
    const int ksplit = 128;
    prepack_feat_kernel<<<dim3(8,32,8), 256, 0, stream>>>(feat, feath);
    conv_mfma4e_kernel<<<dim3(64, 8), 256, 0, stream>>>(feath, wr, conv_b, iam, expi);
    einsum_expi_kernel<<<dim3(ksplit, 1, 8), 256, 0, stream>>>(feat, expi, rowsum, partial);
    fc_head_kernel<<<dim3(NMASK,BATCH), 256, 0, stream>>>(partial, ksplit, rowsum,
        fc_w, fc_b, cls_w, cls_b, mk_w, mk_b, obj_w, obj_b, dout);
  } else {
    // mode B: no-prepass path (v1 conv with expi side-output + expi einsum).
    unsigned short* expiB = (unsigned short*)shared_region;
    unsigned short* partial = (unsigned short*)(shared_region + expib);
    int ksplit = 32;
    conv_mfma_kernel<<<dim3(128, 8), 256, 0, stream>>>(feat, wr, conv_b, iam, expiB);
    einsum_expi_kernel<<<dim3(ksplit, 1, 8), 256, 0, stream>>>(feat, expiB, rowsum, partial);
    fc_head_kernel<<<dim3(NMASK,BATCH), 256, 0, stream>>>(partial, ksplit, rowsum,
        fc_w, fc_b, cls_w, cls_b, mk_w, mk_b, obj_w, obj_b, dout);
  }
}

// Round 26
// 202.150 us; speedup vs baseline: 1.2007x; 1.2007x over previous
//
#include <hip/hip_runtime.h>
#include <math.h>

#define BATCH 8
#define CHAN 256
#define HH 128
#define WW 128
#define NMASK 100
#define HWSZ (HH*WW)
#define KD 128

// d_out layout: [logits 800][kernel 102400][scores 800][iam 13107200]
#define OFF_LOGITS 0
#define OFF_KERNEL 800
#define OFF_SCORES (800 + 800*KD)
#define OFF_IAM    (OFF_SCORES + 800)

typedef __attribute__((ext_vector_type(8))) short bf16x8;
typedef __attribute__((ext_vector_type(8))) unsigned short ushort8;
typedef __attribute__((ext_vector_type(4))) float f32x4;

#define WCHUNK (9*7*64*8)   // ushorts per cc-chunk of packed weights (64.5 KB)

__device__ __forceinline__ unsigned short f2bf(float f){
  unsigned int u = __float_as_uint(f);
  u += 0x7fffu + ((u >> 16) & 1u);
  return (unsigned short)(u >> 16);
}

// ---------------- weight pre-pack (+ rowsum zeroing) ----------------
// wr[(((cc*9+tap)*7+nt)*64+l)*8+j] = bf16(W[n][c][kh][kw])
__global__ __launch_bounds__(256) void wpack_kernel(
    const float* __restrict__ cw, unsigned short* __restrict__ wr,
    float* __restrict__ rowsum)
{
  if (blockIdx.x == 0){
    for (int i = threadIdx.x; i < BATCH*NMASK; i += 256) rowsum[i] = 0.f;
  }
  int i = blockIdx.x*256 + threadIdx.x;
  if (i >= 8*9*7*64*8) return;
  int j = i & 7;
  int l = (i >> 3) & 63;
  int rest = i >> 9;
  int nt = rest % 7;
  int tc = rest / 7;
  int tap = tc % 9;
  int cc  = tc / 9;
  int n = nt*16 + (l & 15);
  int c = cc*32 + (l >> 4)*8 + j;
  float v = 0.f;
  if (n < NMASK) v = cw[((size_t)n*CHAN + c)*9 + tap];
  wr[i] = f2bf(v);
}

// ------- feature prepass: fp32 [b][c][p] -> bf16 [b][cg][p][c8] --------------
__global__ __launch_bounds__(256) void prepack_feat_kernel(
    const float* __restrict__ feat, unsigned short* __restrict__ feath)
{
  const int b  = blockIdx.z;
  const int cg = blockIdx.y;
  const int t  = threadIdx.x;
  __shared__ unsigned short lt[8*264];
  const int cl = t >> 5;           // 0..7
  const int po = (t & 31)*8;       // 0..248
  for (int st=0; st<8; ++st){
    const int P0 = blockIdx.x*2048 + st*256;
    const float* src = feat + ((size_t)(b*CHAN + cg*8 + cl))*HWSZ + P0 + po;
    float4 a0 = *(const float4*)src;
    float4 a1 = *(const float4*)(src+4);
    ushort8 u;
    u[0]=f2bf(a0.x); u[1]=f2bf(a0.y); u[2]=f2bf(a0.z); u[3]=f2bf(a0.w);
    u[4]=f2bf(a1.x); u[5]=f2bf(a1.y); u[6]=f2bf(a1.z); u[7]=f2bf(a1.w);
    *(ushort8*)&lt[cl*264 + po] = u;
    __syncthreads();
    ushort8 v;
    #pragma unroll
    for (int c=0;c<8;c++) v[c] = lt[c*264 + t];
    *(ushort8*)&feath[(((size_t)b*32 + cg)*HWSZ + P0 + t)*8] = v;
    __syncthreads();
  }
}

// ------ conv v4e: A-slab LDS, B direct; epilogue also stores bf16 exp(iam) ------
__global__ __launch_bounds__(256,2) void conv_mfma4e_kernel(
    const unsigned short* __restrict__ feath, const unsigned short* __restrict__ wr,
    const float* __restrict__ cb, float* __restrict__ out_iam,
    unsigned short* __restrict__ expi)
{
  const int h0 = blockIdx.x*2;
  const int b  = blockIdx.y;
  const int t  = threadIdx.x;
  const int w  = t >> 6;
  const int l  = t & 63;
  const int lx = l & 15;
  const int lg = l >> 4;

  __shared__ unsigned short lA[WCHUNK];   // 64,512 B, one weight chunk

  f32x4 acc[7][2][2];   // [nt][row][pi]
  #pragma unroll
  for (int nt=0;nt<7;nt++)
    #pragma unroll
    for (int r=0;r<2;r++)
      #pragma unroll
      for (int pi=0;pi<2;pi++) acc[nt][r][pi] = (f32x4){0.f,0.f,0.f,0.f};

  const unsigned short* fb = feath + ((size_t)b*32 + lg)*HWSZ*8;
  const int xb0 = (w*2+0)*16 + lx - 1;
  const int xb1 = (w*2+1)*16 + lx - 1;

  #pragma unroll 1
  for (int cc=0; cc<8; ++cc){
    __syncthreads();   // prior chunk's LDS reads complete
    {
      const unsigned short* src = wr + (size_t)cc*WCHUNK;
      #pragma unroll
      for (int it=0; it<16; ++it){
        int g2 = it*4 + w;
        if (g2 < 63){
          ushort8 v = *(const ushort8*)(src + ((size_t)g2*64 + l)*8);
          *(ushort8*)&lA[((size_t)g2*64 + l)*8] = v;
        }
      }
    }
    __syncthreads();   // slab visible to all waves

    const unsigned short* fcc = fb + (size_t)cc*4*HWSZ*8;
    #pragma unroll
    for (int tap=0; tap<9; ++tap){
      const int kh = tap/3, kw = tap - 3*(tap/3);
      bf16x8 a[7];
      #pragma unroll
      for (int nt=0;nt<7;nt++)
        a[nt] = *(const bf16x8*)&lA[(((size_t)tap*7+nt)*64 + l)*8];
      bf16x8 bv[2][2];
      #pragma unroll
      for (int r=0;r<2;r++){
        const int hr = h0 + r + kh - 1;
        const bool rvv = (unsigned)hr < 128u;
        const int hc = rvv ? hr : 0;
        #pragma unroll
        for (int pi=0;pi<2;pi++){
          const int X = (pi ? xb1 : xb0) + kw;
          const bool xv = (unsigned)X < 128u;
          const int Xc = xv ? X : 0;
          bf16x8 v2 = *(const bf16x8*)&fcc[((size_t)hc*WW + Xc)*8];
          bv[r][pi] = (rvv && xv) ? v2 : (bf16x8)(short)0;
        }
      }
      #pragma unroll
      for (int nt=0;nt<7;nt++)
        #pragma unroll
        for (int r=0;r<2;r++)
          #pragma unroll
          for (int pi=0;pi<2;pi++)
            acc[nt][r][pi] = __builtin_amdgcn_mfma_f32_16x16x32_bf16(
                a[nt], bv[r][pi], acc[nt][r][pi], 0, 0, 0);
    }
  }

  // Epilogue: D col(x)=lane&15, row(mask)=(lane>>4)*4+q.
  #pragma unroll
  for (int nt=0; nt<7; nt++){
    const int n0 = nt*16 + lg*4;
    #pragma unroll
    for (int r=0; r<2; r++){
      #pragma unroll
      for (int pi=0; pi<2; pi++){
        const int xo = (w*2+pi)*16 + lx;
        #pragma unroll
        for (int q=0; q<4; q++){
          int n = n0 + q;
          if (n < NMASK){
            const float v = acc[nt][r][pi][q] + cb[n];
            const size_t idx = ((size_t)b*NMASK + n)*HWSZ + (h0+r)*WW + xo;
            out_iam[idx] = v;
            expi[idx] = f2bf(__expf(v));
          }
        }
      }
    }
  }
}

// ---------------- conv v1 (fallback for small ws: fp32 staging via LDS) ----------
#define LDSX 40
__global__ __launch_bounds__(256) void conv_mfma_kernel(
    const float* __restrict__ feat, const unsigned short* __restrict__ wr,
    const float* __restrict__ cb, float* __restrict__ out_iam,
    unsigned short* __restrict__ expi)
{
  const int h = blockIdx.x;
  const int b = blockIdx.y;
  const int t = threadIdx.x;
  const int w = t >> 6;
  const int l = t & 63;
  const int lx = l & 15;
  const int lg = l >> 4;

  __shared__ unsigned short lds[3*132*LDSX];

  f32x4 acc[7][2];
  #pragma unroll
  for (int nt=0;nt<7;nt++)
    #pragma unroll
    for (int pi=0;pi<2;pi++) acc[nt][pi] = (f32x4){0.f,0.f,0.f,0.f};

  const float* fb = feat + (size_t)b*CHAN*HWSZ;

  for (int cc=0; cc<8; ++cc){
    const int c0 = cc*32;
    __syncthreads();
    for (int gi = t; gi < 1560; gi += 256){
      int xh = gi % 130;
      int q  = gi / 130;
      int cg = q & 3;
      int kh = q >> 2;
      int row = h + kh - 1;
      int xx  = xh - 1;
      bool ok = ((unsigned)row < 128u) & ((unsigned)xx < 128u);
      const float* src = fb + (size_t)(c0 + cg*8)*HWSZ + row*WW + xx;
      ushort8 u;
      #pragma unroll
      for (int j=0;j<8;j++){
        float v = ok ? src[(size_t)j*HWSZ] : 0.f;
        u[j] = f2bf(v);
      }
      *(ushort8*)&lds[(kh*132 + xh)*LDSX + cg*8] = u;
    }
    __syncthreads();

    const unsigned short* wbase = wr + ((size_t)cc*9*7*64 + l)*8;
    #pragma unroll 1
    for (int tap=0; tap<9; ++tap){
      const int kh = tap / 3;
      const int kw = tap - kh*3;
      bf16x8 a[7];
      #pragma unroll
      for (int nt=0; nt<7; nt++)
        a[nt] = *(const bf16x8*)(wbase + ((size_t)(tap*7 + nt))*64*8);
      bf16x8 bfv[2];
      #pragma unroll
      for (int pi=0; pi<2; pi++){
        int xh = (w*2+pi)*16 + lx + kw;
        bfv[pi] = *(const bf16x8*)&lds[(kh*132 + xh)*LDSX + lg*8];
      }
      #pragma unroll
      for (int nt=0; nt<7; nt++)
        #pragma unroll
        for (int pi=0; pi<2; pi++)
          acc[nt][pi] = __builtin_amdgcn_mfma_f32_16x16x32_bf16(
              a[nt], bfv[pi], acc[nt][pi], 0, 0, 0);
    }
  }

  #pragma unroll
  for (int nt=0; nt<7; nt++){
    const int n0 = nt*16 + lg*4;
    #pragma unroll
    for (int pi=0; pi<2; pi++){
      const int xo = (w*2+pi)*16 + lx;
      #pragma unroll
      for (int r=0; r<4; r++){
        int n = n0 + r;
        if (n < NMASK){
          const float v = acc[nt][pi][r] + cb[n];
          const size_t idx = ((size_t)b*NMASK + n)*HWSZ + h*WW + xo;
          out_iam[idx] = v;
          expi[idx] = f2bf(__expf(v));
        }
      }
    }
  }
}

// -------- einsum: A = bf16 exp(iam) direct; rowsum from bf16; bf16 partial ----
// partial_bf[s][b][n][c] = bf16(sum_p expi[n,p]*F[c,p]) (unnormalized).
__global__ __launch_bounds__(256) void einsum_expi_kernel(
  const float* __restrict__ feat, const unsigned short* __restrict__ expi,
  float* __restrict__ rowsum, unsigned short* __restrict__ partial)
{
  const int s = blockIdx.x;
  const int nsplit = gridDim.x;
  const int KC = HWSZ / nsplit;
  const int b = blockIdx.z;
  const int t = threadIdx.x;
  const int w = t >> 6;
  const int l = t & 63;
  const int lx = l & 15;
  const int lg = l >> 4;

  f32x4 acc[7][4];
  #pragma unroll
  for (int nt=0;nt<7;nt++)
    #pragma unroll
    for (int j=0;j<4;j++) acc[nt][j] = (f32x4){0.f,0.f,0.f,0.f};

  float se[7];
  #pragma unroll
  for (int nt=0;nt<7;nt++) se[nt] = 0.f;

  int rown[7];
  #pragma unroll
  for (int nt=0;nt<7;nt++){
    int row = nt*16 + lx;
    if (row >= NMASK) row = NMASK-1;
    rown[nt] = row;
  }

  const float* fb = feat + (size_t)b*CHAN*HWSZ;
  const unsigned short* eb = expi + (size_t)b*NMASK*HWSZ;

  #pragma unroll 2
  for (int ks=0; ks<KC/32; ++ks){
    const int p0 = s*KC + ks*32 + lg*8;
    bf16x8 afr[7];
    #pragma unroll
    for (int nt=0;nt<7;nt++){
      ushort8 u = *(const ushort8*)(eb + (size_t)rown[nt]*HWSZ + p0);
      #pragma unroll
      for (int j=0;j<8;j++)
        se[nt] += __uint_as_float((unsigned)u[j] << 16);
      afr[nt] = *(bf16x8*)&u;
    }
    bf16x8 bfr[4];
    #pragma unroll
    for (int j=0;j<4;j++){
      const float* fp = fb + (size_t)(w*64 + j*16 + lx)*HWSZ + p0;
      float4 b0 = *(const float4*)fp;
      float4 b1 = *(const float4*)(fp+4);
      ushort8 u;
      u[0]=f2bf(b0.x); u[1]=f2bf(b0.y); u[2]=f2bf(b0.z); u[3]=f2bf(b0.w);
      u[4]=f2bf(b1.x); u[5]=f2bf(b1.y); u[6]=f2bf(b1.z); u[7]=f2bf(b1.w);
      bfr[j] = *(bf16x8*)&u;
    }
    #pragma unroll
    for (int nt=0;nt<7;nt++)
      #pragma unroll
      for (int j=0;j<4;j++)
        acc[nt][j] = __builtin_amdgcn_mfma_f32_16x16x32_bf16(
            afr[nt], bfr[j], acc[nt][j], 0, 0, 0);
  }

  // rowsum contribution: reduce across lg groups (same lx), wave 0 only.
  if (w == 0){
    #pragma unroll
    for (int nt=0;nt<7;nt++){
      float sv = se[nt];
      sv += __shfl_xor(sv, 16);
      sv += __shfl_xor(sv, 32);
      int row = nt*16 + l;          // l < 16 lanes are canonical
      if (l < 16 && row < NMASK)
        atomicAdd(&rowsum[b*NMASK + row], sv);
    }
  }

  #pragma unroll
  for (int nt=0;nt<7;nt++){
    #pragma unroll
    for (int j=0;j<4;j++){
      const int c = w*64 + j*16 + lx;
      #pragma unroll
      for (int r=0;r<4;r++){
        int n = nt*16 + lg*4 + r;
        if (n < NMASK)
          partial[(((size_t)b*nsplit + s)*NMASK + n)*CHAN + c] = f2bf(acc[nt][j][r]);
      }
    }
  }
}

// ---------- fc + heads with VECTORIZED bf16 partial reduction ----------
// Phase 1: thread t = (group g = t>>5, ch8 = t&31); each thread accumulates
// 8 channels (ushort8 loads, 16B/lane) over s = g, g+8, ...; LDS reduce across
// the 8 groups hands channel t its total.
__global__ __launch_bounds__(256) void fc_head_kernel(
  const unsigned short* __restrict__ partial, int nsplit,
  const float* __restrict__ rowsum,
  const float* __restrict__ fc_w, const float* __restrict__ fc_b,
  const float* __restrict__ cls_w, const float* __restrict__ cls_b,
  const float* __restrict__ mk_w, const float* __restrict__ mk_b,
  const float* __restrict__ obj_w, const float* __restrict__ obj_b,
  float* __restrict__ dout)
{
  const int n = blockIdx.x;
  const int b = blockIdx.y;
  const int t = threadIdx.x;
  const int g   = t >> 5;        // 0..7 (s-offset group)
  const int ch8 = t & 31;        // 8-channel chunk index
  __shared__ float redv[8*264];  // [group][channel] partial sums (8448 B)
  __shared__ float xs[256];
  __shared__ float xr[256];
  __shared__ float red[256];

  float av[8];
  #pragma unroll
  for (int j=0;j<8;j++) av[j] = 0.f;
  for (int s = g; s < nsplit; s += 8){
    ushort8 u = *(const ushort8*)&partial[(((size_t)b*nsplit + s)*NMASK + n)*CHAN + ch8*8];
    #pragma unroll
    for (int j=0;j<8;j++)
      av[j] += __uint_as_float((unsigned)u[j] << 16);
  }
  #pragma unroll
  for (int j=0;j<8;j++) redv[g*264 + ch8*8 + j] = av[j];
  __syncthreads();
  float x = 0.f;
  #pragma unroll
  for (int gg=0; gg<8; gg++) x += redv[gg*264 + t];
  x *= (1.0f / rowsum[b*NMASK + n]);   // softmax normalization, deferred
  xs[t] = x;
  __syncthreads();
  float y = fc_b[t];
  const float* wr2 = fc_w + (size_t)t*CHAN;
  for (int k=0;k<CHAN;k+=4){
    float4 w4 = *(const float4*)&wr2[k];
    y = fmaf(xs[k],w4.x,y); y=fmaf(xs[k+1],w4.y,y);
    y = fmaf(xs[k+2],w4.z,y); y=fmaf(xs[k+3],w4.w,y);
  }
  y = fmaxf(y, 0.f);
  xr[t] = y;
  __syncthreads();
  if (t < KD){
    float ka = mk_b[t];
    const float* mr = mk_w + (size_t)t*CHAN;
    for (int k=0;k<CHAN;k+=4){
      float4 w4 = *(const float4*)&mr[k];
      ka = fmaf(xr[k],w4.x,ka); ka=fmaf(xr[k+1],w4.y,ka);
      ka = fmaf(xr[k+2],w4.z,ka); ka=fmaf(xr[k+3],w4.w,ka);
    }
    dout[OFF_KERNEL + ((size_t)b*NMASK + n)*KD + t] = ka;
  }
  red[t] = xr[t] * cls_w[t];
  __syncthreads();
  for (int s2=128;s2>0;s2>>=1){ if(t<s2) red[t]+=red[t+s2]; __syncthreads(); }
  if (t==0) dout[OFF_LOGITS + (size_t)b*NMASK + n] = red[0] + cls_b[0];
  __syncthreads();
  red[t] = xr[t] * obj_w[t];
  __syncthreads();
  for (int s2=128;s2>0;s2>>=1){ if(t<s2) red[t]+=red[t+s2]; __syncthreads(); }
  if (t==0) dout[OFF_SCORES + (size_t)b*NMASK + n] = red[0] + obj_b[0];
}

extern "C" void kernel_launch(void* const* d_in, const int* in_sizes, int n_in,
                              void* d_out, int out_size, void* d_ws, size_t ws_size,
                              hipStream_t stream)
{
  const float* feat   = (const float*)d_in[0];
  const float* conv_w = (const float*)d_in[1];
  const float* conv_b = (const float*)d_in[2];
  // d_in[3] = softmax_bias: scalar shift, softmax-invariant -> unused
  const float* fc_w   = (const float*)d_in[4];
  const float* fc_b   = (const float*)d_in[5];
  const float* cls_w  = (const float*)d_in[6];
  const float* cls_b  = (const float*)d_in[7];
  const float* mk_w   = (const float*)d_in[8];
  const float* mk_b   = (const float*)d_in[9];
  const float* obj_w  = (const float*)d_in[10];
  const float* obj_b  = (const float*)d_in[11];
  float* dout = (float*)d_out;
  float* iam  = dout + OFF_IAM;

  const size_t statb  = 1600*sizeof(float);                 // rowsum uses 3200
  const size_t wrb    = (size_t)8*WCHUNK*2;                 // 516096
  const size_t feathb = (size_t)BATCH*32*HWSZ*8*2;          // 67,108,864
  const size_t expib  = (size_t)BATCH*NMASK*HWSZ*2;         // 26,214,400

  float* rowsum = (float*)d_ws;
  unsigned short* wr = (unsigned short*)((char*)d_ws + statb);
  char* shared_region = (char*)d_ws + statb + wrb;          // feath | partial alias
  unsigned short* expi = (unsigned short*)(shared_region + feathb);

  wpack_kernel<<<dim3((8*WCHUNK + 255)/256), 256, 0, stream>>>(conv_w, wr, rowsum);

  if (ws_size >= statb + wrb + feathb + expib + 1024){
    // mode A (round-24 config): prepass + v4e conv + expi einsum at ksplit=64;
    // bf16 partial (26.2 MB) aliases feath (67 MB, disjoint lifetimes).
    unsigned short* feath = (unsigned short*)shared_region;
    unsigned short* partial = (unsigned short*)shared_region;
    const int ksplit = 64;
    prepack_feat_kernel<<<dim3(8,32,8), 256, 0, stream>>>(feat, feath);
    conv_mfma4e_kernel<<<dim3(64, 8), 256, 0, stream>>>(feath, wr, conv_b, iam, expi);
    einsum_expi_kernel<<<dim3(ksplit, 1, 8), 256, 0, stream>>>(feat, expi, rowsum, partial);
    fc_head_kernel<<<dim3(NMASK,BATCH), 256, 0, stream>>>(partial, ksplit, rowsum,
        fc_w, fc_b, cls_w, cls_b, mk_w, mk_b, obj_w, obj_b, dout);
  } else {
    // mode B: no-prepass path (v1 conv with expi side-output + expi einsum).
    unsigned short* expiB = (unsigned short*)shared_region;
    unsigned short* partial = (unsigned short*)(shared_region + expib);
    int ksplit = 32;
    conv_mfma_kernel<<<dim3(128, 8), 256, 0, stream>>>(feat, wr, conv_b, iam, expiB);
    einsum_expi_kernel<<<dim3(ksplit, 1, 8), 256, 0, stream>>>(feat, expiB, rowsum, partial);
    fc_head_kernel<<<dim3(NMASK,BATCH), 256, 0, stream>>>(partial, ksplit, rowsum,
        fc_w, fc_b, cls_w, cls_b, mk_w, mk_b, obj_w, obj_b, dout);
  }
}